// Round 9
// baseline (1062.838 us; speedup 1.0000x reference)
//
#include <hip/hip_runtime.h>
#include <math.h>

#define SEQ   2048
#define HID   1024
#define INTER 2048
#define DST   16
#define DTR   64
#define NP    96   // DTR + 2*DST
#define NC    64   // scan chunks
#define LCH   32   // steps per chunk (NC*LCH == SEQ)
#define KS    16   // split-K factor for h @ W_x
#define REPN  8    // diagnostic replication factor

typedef _Float16 f16;
typedef _Float16 f16x8 __attribute__((ext_vector_type(8)));
typedef _Float16 f16x4v __attribute__((ext_vector_type(4)));
typedef float f32x4 __attribute__((ext_vector_type(4)));

__device__ __forceinline__ float sigmoidf_(float x) { return 1.0f / (1.0f + expf(-x)); }
__device__ __forceinline__ float siluf_(float x)    { return x * sigmoidf_(x); }
__device__ __forceinline__ float softplusf_(float x){ return (x > 20.0f) ? x : log1pf(expf(x)); }

// XCD-aware bijective block swizzle (requires nwg % 8 == 0).
__device__ __forceinline__ int xcd_swz(int bid, int nwg)
{
    int cpx = nwg >> 3;
    return (bid & 7) * cpx + (bid >> 3);
}

// ---------------------------------------------------------------------------
// prep_all (x8): x->f16 + all 4 weight transposes.
// ---------------------------------------------------------------------------
__device__ __forceinline__ void tile_transpose(const float* __restrict__ W,
                                               f16* __restrict__ Wt,
                                               int K, int N, int bx, int by, int tid)
{
    __shared__ float t[32][33];
    const int n0 = bx * 32, k0 = by * 32;
    const int j = tid & 31, i0 = tid >> 5;
#pragma unroll
    for (int r = 0; r < 4; ++r)
        t[i0 + r * 8][j] = W[(size_t)(k0 + i0 + r * 8) * N + n0 + j];
    __syncthreads();
#pragma unroll
    for (int r = 0; r < 4; ++r)
        Wt[(size_t)(n0 + i0 + r * 8) * K + k0 + j] = (f16)t[j][i0 + r * 8];
}

__global__ __launch_bounds__(256) void prep_all(const float* __restrict__ x,
                                                const float* __restrict__ W_in,
                                                const float* __restrict__ W_out,
                                                const float* __restrict__ W_x,
                                                const float* __restrict__ W_dt,
                                                f16* __restrict__ xh,
                                                f16* __restrict__ W_in_t,
                                                f16* __restrict__ W_out_t,
                                                f16* __restrict__ WxT,
                                                f16* __restrict__ WdtT,
                                                int repn)
{
    const int bid = blockIdx.x, tid = threadIdx.x;
    for (int rep = 0; rep < repn; ++rep) {
        asm volatile("" ::: "memory");
        if (bid < 2048) {
            int i = (bid * 256 + tid) * 4;
            float4 v = *(const float4*)&x[i];
            f16x4v o;
            o.x = (f16)v.x; o.y = (f16)v.y; o.z = (f16)v.z; o.w = (f16)v.w;
            *(f16x4v*)&xh[i] = o;
        } else if (bid < 6144) {
            int t = bid - 2048;
            tile_transpose(W_in, W_in_t, HID, 4096, t & 127, t >> 7, tid);
        } else if (bid < 8192) {
            int t = bid - 6144;
            tile_transpose(W_out, W_out_t, INTER, HID, t & 31, t >> 5, tid);
        } else if (bid < 8384) {
            int t = bid - 8192;
            tile_transpose(W_x, WxT, INTER, NP, t % 3, t / 3, tid);
        } else {
            int t = bid - 8384;
            tile_transpose(W_dt, WdtT, DTR, INTER, t & 63, t >> 6, tid);
        }
        __syncthreads();
    }
}

// ---------------------------------------------------------------------------
// Split-K MFMA f16 GEMM (x8), m97 staging structure.
// ---------------------------------------------------------------------------
template<int BM, int BN, int KTOT, int KCH>
__global__ __launch_bounds__(256) void gemm_sk_f16(const f16* __restrict__ Ah,
                                                   const f16* __restrict__ Bt,
                                                   f16* __restrict__ planes,
                                                   int N, int nbx, int nby,
                                                   int repn)
{
    constexpr int BK = 64;
    __shared__ __align__(16) f16 As[BM * BK];
    __shared__ __align__(16) f16 Bs[BN * BK];

    const int tile = xcd_swz(blockIdx.x, gridDim.x);
    const int bx = tile % nbx;
    const int rem = tile / nbx;
    const int by = rem % nby;
    const int ks = rem / nby;

    const int tid = threadIdx.x;
    const int wid = tid >> 6, lane = tid & 63;
    const int wr = wid >> 1, wc = wid & 1;
    const int m0 = by * BM, n0 = bx * BN;
    const int l15 = lane & 15, lhi = lane >> 4;

    constexpr int MR = BM / 32;
    constexpr int NR = BN / 32;

    for (int rep = 0; rep < repn; ++rep) {
        asm volatile("" ::: "memory");
        f32x4 acc[MR][NR] = {};

        for (int k0 = ks * KCH; k0 < ks * KCH + KCH; k0 += BK) {
            constexpr int CA = BM * BK * 2 / 1024;
#pragma unroll
            for (int c0 = 0; c0 < CA; c0 += 4) {
                int c = c0 + wid;
                int e = c * 64 + lane;
                int row = e >> 3, seg = e & 7;
                __builtin_amdgcn_global_load_lds(
                    (const __attribute__((address_space(1))) unsigned int*)
                        (Ah + (size_t)(m0 + row) * KTOT + k0 + seg * 8),
                    (__attribute__((address_space(3))) unsigned int*)(As + c * 512),
                    16, 0, 0);
            }
            constexpr int CB = BN * BK * 2 / 1024;
#pragma unroll
            for (int c0 = 0; c0 < CB; c0 += 4) {
                int c = c0 + wid;
                int e = c * 64 + lane;
                int row = e >> 3, seg = e & 7;
                __builtin_amdgcn_global_load_lds(
                    (const __attribute__((address_space(1))) unsigned int*)
                        (Bt + (size_t)(n0 + row) * KTOT + k0 + seg * 8),
                    (__attribute__((address_space(3))) unsigned int*)(Bs + c * 512),
                    16, 0, 0);
            }
            __syncthreads();

#pragma unroll
            for (int kk = 0; kk < BK; kk += 32) {
                f16x8 af[MR], bf[NR];
#pragma unroll
                for (int i = 0; i < MR; ++i)
                    af[i] = *(const f16x8*)&As[(wr * (BM / 2) + i * 16 + l15) * BK + kk + lhi * 8];
#pragma unroll
                for (int n = 0; n < NR; ++n)
                    bf[n] = *(const f16x8*)&Bs[(wc * (BN / 2) + n * 16 + l15) * BK + kk + lhi * 8];
#pragma unroll
                for (int i = 0; i < MR; ++i)
#pragma unroll
                    for (int n = 0; n < NR; ++n)
                        acc[i][n] = __builtin_amdgcn_mfma_f32_16x16x32_f16(af[i], bf[n], acc[i][n], 0, 0, 0);
            }
            __syncthreads();
        }

        f16* C = planes + (size_t)ks * ((size_t)nby * BM * N);
#pragma unroll
        for (int i = 0; i < MR; ++i)
#pragma unroll
            for (int n = 0; n < NR; ++n)
#pragma unroll
                for (int r = 0; r < 4; ++r)
                    C[(size_t)(m0 + wr * (BM / 2) + i * 16 + lhi * 4 + r) * N
                      + n0 + wc * (BN / 2) + n * 16 + l15] = (f16)acc[i][n][r];
        __syncthreads();
    }
}

// ---------------------------------------------------------------------------
// conv_gate (x8): raw cols -> h = silu(conv+b); gate cols -> gateh = p0+p1.
// ---------------------------------------------------------------------------
__global__ __launch_bounds__(256) void conv_gate(const f16* __restrict__ pA,
                                                 const float* __restrict__ cw,
                                                 const float* __restrict__ cb,
                                                 f16* __restrict__ hh,
                                                 f16* __restrict__ gateh,
                                                 int repn)
{
    const f16* p1 = pA + (size_t)SEQ * 4096;
    int idx = blockIdx.x * 256 + threadIdx.x;
    int cu = idx & 511;
    int s = idx >> 9;
    int col = cu * 8;
    for (int rep = 0; rep < repn; ++rep) {
        asm volatile("" ::: "memory");
        if (col < INTER) {
            float acc[8];
#pragma unroll
            for (int j = 0; j < 8; ++j) acc[j] = cb[col + j];
#pragma unroll
            for (int k = 0; k < 4; ++k) {
                int sp = s + k - 3;
                if (sp >= 0) {
                    f16x8 a = *(const f16x8*)&pA[(size_t)sp * 4096 + col];
                    f16x8 b = *(const f16x8*)&p1[(size_t)sp * 4096 + col];
#pragma unroll
                    for (int j = 0; j < 8; ++j)
                        acc[j] = fmaf((float)a[j] + (float)b[j], cw[k * INTER + col + j], acc[j]);
                }
            }
            f16x8 o;
#pragma unroll
            for (int j = 0; j < 8; ++j) o[j] = (f16)siluf_(acc[j]);
            *(f16x8*)&hh[(size_t)s * INTER + col] = o;
        } else {
            int g = col - INTER;
            f16x8 a = *(const f16x8*)&pA[(size_t)s * 4096 + col];
            f16x8 b = *(const f16x8*)&p1[(size_t)s * 4096 + col];
            f16x8 o;
#pragma unroll
            for (int j = 0; j < 8; ++j) o[j] = (f16)((float)a[j] + (float)b[j]);
            *(f16x8*)&gateh[(size_t)s * INTER + g] = o;
        }
    }
}

// ---------------------------------------------------------------------------
// hwx (x8): partials[ks][SEQ][96] f16
// ---------------------------------------------------------------------------
__global__ __launch_bounds__(256) void hwx_mfma(const f16* __restrict__ hh,
                                                const f16* __restrict__ WxT,
                                                f16* __restrict__ partials,
                                                int repn)
{
    constexpr int BM = 128, BN = 96, BK = 64;
    __shared__ __align__(16) f16 As[BM * BK];
    __shared__ __align__(16) f16 Bs[BN * BK];

    const int tile = xcd_swz(blockIdx.x, gridDim.x);
    const int bxm = tile & 15, ks = tile >> 4;

    const int tid = threadIdx.x;
    const int wid = tid >> 6, lane = tid & 63;
    const int wr = wid >> 1, wc = wid & 1;
    const int m0 = bxm * BM;
    const int l15 = lane & 15, lhi = lane >> 4;

    constexpr int MR = 4, NR = 3;
    for (int rep = 0; rep < repn; ++rep) {
        asm volatile("" ::: "memory");
        f32x4 acc[MR][NR] = {};

        for (int k0 = ks * 128; k0 < ks * 128 + 128; k0 += BK) {
#pragma unroll
            for (int c0 = 0; c0 < 16; c0 += 4) {
                int c = c0 + wid;
                int e = c * 64 + lane;
                int row = e >> 3, seg = e & 7;
                __builtin_amdgcn_global_load_lds(
                    (const __attribute__((address_space(1))) unsigned int*)
                        (hh + (size_t)(m0 + row) * INTER + k0 + seg * 8),
                    (__attribute__((address_space(3))) unsigned int*)(As + c * 512),
                    16, 0, 0);
            }
#pragma unroll
            for (int c0 = 0; c0 < 12; c0 += 4) {
                int c = c0 + wid;
                int e = c * 64 + lane;
                int row = e >> 3, seg = e & 7;
                __builtin_amdgcn_global_load_lds(
                    (const __attribute__((address_space(1))) unsigned int*)
                        (WxT + (size_t)row * INTER + k0 + seg * 8),
                    (__attribute__((address_space(3))) unsigned int*)(Bs + c * 512),
                    16, 0, 0);
            }
            __syncthreads();

#pragma unroll
            for (int kk = 0; kk < BK; kk += 32) {
                f16x8 af[MR], bf[NR];
#pragma unroll
                for (int i = 0; i < MR; ++i)
                    af[i] = *(const f16x8*)&As[(wr * 64 + i * 16 + l15) * BK + kk + lhi * 8];
#pragma unroll
                for (int n = 0; n < NR; ++n)
                    bf[n] = *(const f16x8*)&Bs[(wc * 48 + n * 16 + l15) * BK + kk + lhi * 8];
#pragma unroll
                for (int i = 0; i < MR; ++i)
#pragma unroll
                    for (int n = 0; n < NR; ++n)
                        acc[i][n] = __builtin_amdgcn_mfma_f32_16x16x32_f16(af[i], bf[n], acc[i][n], 0, 0, 0);
            }
            __syncthreads();
        }

        f16* P = partials + (size_t)ks * (SEQ * NP);
#pragma unroll
        for (int i = 0; i < MR; ++i)
#pragma unroll
            for (int n = 0; n < NR; ++n)
#pragma unroll
                for (int r = 0; r < 4; ++r)
                    P[(size_t)(m0 + wr * 64 + i * 16 + lhi * 4 + r) * NP
                      + wc * 48 + n * 16 + l15] = (f16)acc[i][n][r];
        __syncthreads();
    }
}

// ---------------------------------------------------------------------------
// reduce_partials (x8)
// ---------------------------------------------------------------------------
__global__ __launch_bounds__(256) void reduce_partials(const f16* __restrict__ partials,
                                                       float* __restrict__ ssm_p,
                                                       f16* __restrict__ tsh,
                                                       int repn)
{
    int t = blockIdx.x * 256 + threadIdx.x;
    int i8 = t * 8;
    int s = i8 / NP, j0 = i8 % NP;
    for (int rep = 0; rep < repn; ++rep) {
        asm volatile("" ::: "memory");
        float a[8] = {};
#pragma unroll
        for (int c = 0; c < KS; ++c) {
            f16x8 v = *(const f16x8*)&partials[(size_t)c * (SEQ * NP) + i8];
#pragma unroll
            for (int j = 0; j < 8; ++j) a[j] += (float)v[j];
        }
        if (j0 < DTR) {
            f16x8 o;
#pragma unroll
            for (int j = 0; j < 8; ++j) o[j] = (f16)a[j];
            *(f16x8*)&tsh[(size_t)s * DTR + j0] = o;
        } else {
            *(float4*)&ssm_p[(size_t)s * NP + j0]     = make_float4(a[0], a[1], a[2], a[3]);
            *(float4*)&ssm_p[(size_t)s * NP + j0 + 4] = make_float4(a[4], a[5], a[6], a[7]);
        }
    }
}

// ---------------------------------------------------------------------------
// dt_mfma (x8)
// ---------------------------------------------------------------------------
__global__ __launch_bounds__(256) void dt_mfma(const f16* __restrict__ tsh,
                                               const f16* __restrict__ WdtT,
                                               const float* __restrict__ bdt,
                                               f16* __restrict__ dtbh,
                                               int repn)
{
    constexpr int BM = 128, BN = 128, BK = 64;
    __shared__ __align__(16) f16 As[BM * BK];
    __shared__ __align__(16) f16 Bs[BN * BK];

    const int tile = xcd_swz(blockIdx.x, gridDim.x);
    const int bx = tile & 15, by = tile >> 4;

    const int tid = threadIdx.x;
    const int wid = tid >> 6, lane = tid & 63;
    const int wr = wid >> 1, wc = wid & 1;
    const int m0 = by * BM, n0 = bx * BN;
    const int l15 = lane & 15, lhi = lane >> 4;

    constexpr int MR = 4, NR = 4;
    for (int rep = 0; rep < repn; ++rep) {
        asm volatile("" ::: "memory");
        f32x4 acc[MR][NR] = {};

#pragma unroll
        for (int c0 = 0; c0 < 16; c0 += 4) {
            int c = c0 + wid;
            int e = c * 64 + lane;
            int row = e >> 3, seg = e & 7;
            __builtin_amdgcn_global_load_lds(
                (const __attribute__((address_space(1))) unsigned int*)
                    (tsh + (size_t)(m0 + row) * DTR + seg * 8),
                (__attribute__((address_space(3))) unsigned int*)(As + c * 512),
                16, 0, 0);
            __builtin_amdgcn_global_load_lds(
                (const __attribute__((address_space(1))) unsigned int*)
                    (WdtT + (size_t)(n0 + row) * DTR + seg * 8),
                (__attribute__((address_space(3))) unsigned int*)(Bs + c * 512),
                16, 0, 0);
        }
        __syncthreads();

#pragma unroll
        for (int kk = 0; kk < 64; kk += 32) {
            f16x8 af[MR], bf[NR];
#pragma unroll
            for (int i = 0; i < MR; ++i)
                af[i] = *(const f16x8*)&As[(wr * 64 + i * 16 + l15) * BK + kk + lhi * 8];
#pragma unroll
            for (int n = 0; n < NR; ++n)
                bf[n] = *(const f16x8*)&Bs[(wc * 64 + n * 16 + l15) * BK + kk + lhi * 8];
#pragma unroll
            for (int i = 0; i < MR; ++i)
#pragma unroll
                for (int n = 0; n < NR; ++n)
                    acc[i][n] = __builtin_amdgcn_mfma_f32_16x16x32_f16(af[i], bf[n], acc[i][n], 0, 0, 0);
        }

#pragma unroll
        for (int i = 0; i < MR; ++i)
#pragma unroll
            for (int n = 0; n < NR; ++n) {
                int col = n0 + wc * 64 + n * 16 + l15;
                float bv = bdt[col];
#pragma unroll
                for (int r = 0; r < 4; ++r)
                    dtbh[(size_t)(m0 + wr * 64 + i * 16 + lhi * 4 + r) * INTER + col] =
                        (f16)softplusf_(acc[i][n][r] + bv);
            }
        __syncthreads();
    }
}

// ---------------------------------------------------------------------------
// Chunked parallel scan (x8 each)
// ---------------------------------------------------------------------------
__global__ __launch_bounds__(256) void ssm_pass1(const f16* __restrict__ dtbh,
                                                 const f16* __restrict__ hh,
                                                 const float* __restrict__ ssm_p,
                                                 const float* __restrict__ A_log,
                                                 float* __restrict__ Sbuf,
                                                 float* __restrict__ Pbuf,
                                                 int repn)
{
    const int h = blockIdx.x * 256 + threadIdx.x;
    const int c = blockIdx.y;
    const int s0 = c * LCH;
    __shared__ float Bs[LCH][DST];

    for (int rep = 0; rep < repn; ++rep) {
        asm volatile("" ::: "memory");
        for (int j = threadIdx.x; j < LCH * DST; j += 256) {
            int r = j >> 4, dd = j & 15;
            Bs[r][dd] = ssm_p[(size_t)(s0 + r) * NP + DTR + dd];
        }
        __syncthreads();

        float A[DST], st[DST];
#pragma unroll
        for (int d = 0; d < DST; ++d) {
            A[d] = -__expf(A_log[(size_t)h * DST + d]);
            st[d] = 0.0f;
        }

        float dtsum = 0.0f;
        for (int r = 0; r < LCH; ++r) {
            float dtv = (float)dtbh[(size_t)(s0 + r) * INTER + h];
            float hv  = (float)hh[(size_t)(s0 + r) * INTER + h];
            float dh = dtv * hv;
            dtsum += dtv;
#pragma unroll
            for (int d = 0; d < DST; ++d) {
                float da = __expf(dtv * A[d]);
                st[d] = fmaf(da, st[d], dh * Bs[r][d]);
            }
        }

        size_t base = ((size_t)c * INTER + h) * DST;
#pragma unroll
        for (int d = 0; d < DST; d += 4) {
            *(float4*)&Sbuf[base + d] = make_float4(st[d], st[d+1], st[d+2], st[d+3]);
            float4 p4;
            p4.x = __expf(A[d]     * dtsum);
            p4.y = __expf(A[d + 1] * dtsum);
            p4.z = __expf(A[d + 2] * dtsum);
            p4.w = __expf(A[d + 3] * dtsum);
            *(float4*)&Pbuf[base + d] = p4;
        }
        __syncthreads();
    }
}

__global__ __launch_bounds__(256) void ssm_pass2(const float* __restrict__ Sbuf,
                                                 const float* __restrict__ Pbuf,
                                                 float* __restrict__ Cin,
                                                 int repn)
{
    int i = blockIdx.x * 256 + threadIdx.x;
    for (int rep = 0; rep < repn; ++rep) {
        asm volatile("" ::: "memory");
        float carry = 0.0f;
#pragma unroll 8
        for (int c = 0; c < NC; ++c) {
            size_t idx = (size_t)c * (INTER * DST) + i;
            Cin[idx] = carry;
            carry = fmaf(Pbuf[idx], carry, Sbuf[idx]);
        }
    }
}

__global__ __launch_bounds__(256) void ssm_pass3(const f16* __restrict__ dtbh,
                                                 const f16* __restrict__ hh,
                                                 const float* __restrict__ ssm_p,
                                                 const f16* __restrict__ gateh,
                                                 const float* __restrict__ A_log,
                                                 const float* __restrict__ Dvec,
                                                 const float* __restrict__ Cin,
                                                 f16* __restrict__ yh,
                                                 int repn)
{
    const int h = blockIdx.x * 256 + threadIdx.x;
    const int c = blockIdx.y;
    const int s0 = c * LCH;
    __shared__ float Bs[LCH][DST];
    __shared__ float Cs[LCH][DST];

    for (int rep = 0; rep < repn; ++rep) {
        asm volatile("" ::: "memory");
        for (int j = threadIdx.x; j < LCH * DST; j += 256) {
            int r = j >> 4, dd = j & 15;
            Bs[r][dd] = ssm_p[(size_t)(s0 + r) * NP + DTR + dd];
            Cs[r][dd] = ssm_p[(size_t)(s0 + r) * NP + DTR + DST + dd];
        }
        __syncthreads();

        float A[DST], st[DST];
        size_t base = ((size_t)c * INTER + h) * DST;
#pragma unroll
        for (int d = 0; d < DST; ++d) {
            A[d] = -__expf(A_log[(size_t)h * DST + d]);
            st[d] = Cin[base + d];
        }
        const float Dv = Dvec[h];

        for (int r = 0; r < LCH; ++r) {
            float dtv = (float)dtbh[(size_t)(s0 + r) * INTER + h];
            float hv  = (float)hh[(size_t)(s0 + r) * INTER + h];
            float g   = (float)gateh[(size_t)(s0 + r) * INTER + h];
            float dh = dtv * hv;
            float y = 0.0f;
#pragma unroll
            for (int d = 0; d < DST; ++d) {
                float da = __expf(dtv * A[d]);
                st[d] = fmaf(da, st[d], dh * Bs[r][d]);
                y = fmaf(st[d], Cs[r][d], y);
            }
            y = fmaf(hv, Dv, y);
            yh[(size_t)(s0 + r) * INTER + h] = (f16)(y * siluf_(g));
        }
        __syncthreads();
    }
}

// ---------------------------------------------------------------------------
// reduce_out (x8)
// ---------------------------------------------------------------------------
__global__ __launch_bounds__(256) void reduce_out(const f16* __restrict__ pY,
                                                  float* __restrict__ out,
                                                  int repn)
{
    int i8 = (blockIdx.x * 256 + threadIdx.x) * 8;
    for (int rep = 0; rep < repn; ++rep) {
        asm volatile("" ::: "memory");
        f16x8 a = *(const f16x8*)&pY[i8];
        f16x8 b = *(const f16x8*)&pY[(size_t)SEQ * HID + i8];
        float4 o1, o2;
        o1.x = (float)a[0] + (float)b[0];
        o1.y = (float)a[1] + (float)b[1];
        o1.z = (float)a[2] + (float)b[2];
        o1.w = (float)a[3] + (float)b[3];
        o2.x = (float)a[4] + (float)b[4];
        o2.y = (float)a[5] + (float)b[5];
        o2.z = (float)a[6] + (float)b[6];
        o2.w = (float)a[7] + (float)b[7];
        *(float4*)&out[i8]     = o1;
        *(float4*)&out[i8 + 4] = o2;
    }
}

// ---------------------------------------------------------------------------
extern "C" void kernel_launch(void* const* d_in, const int* in_sizes, int n_in,
                              void* d_out, int out_size, void* d_ws, size_t ws_size,
                              hipStream_t stream)
{
    const float* x      = (const float*)d_in[0];
    const float* W_in   = (const float*)d_in[1];
    const float* conv_w = (const float*)d_in[2];
    const float* conv_b = (const float*)d_in[3];
    const float* W_x    = (const float*)d_in[4];
    const float* W_dt   = (const float*)d_in[5];
    const float* b_dt   = (const float*)d_in[6];
    const float* A_log  = (const float*)d_in[7];
    const float* Dv     = (const float*)d_in[8];
    const float* W_out  = (const float*)d_in[9];
    float* out = (float*)d_out;

    float* ws = (float*)d_ws;
    f16*  pA     = (f16*)ws;                     // 2 planes x SEQ x 4096
    f16*  hh     = (f16*)(ws + 8388608);
    f16*  gateh  = (f16*)(ws + 10485760);
    f16*  dtbh   = (f16*)(ws + 12582912);
    f16*  yh     = (f16*)(ws + 14680064);
    f16*  xh     = (f16*)(ws + 16777216);
    f16*  W_in_t = (f16*)(ws + 17825792);
    f16*  W_out_t= (f16*)(ws + 19922944);
    f16*  WxT    = (f16*)(ws + 20971520);
    f16*  tsh    = (f16*)(ws + 21069824);
    f16*  WdtT   = (f16*)(ws + 21135360);
    float* ssm_p = ws + 21200896;
    f16*  parts  = (f16*)(ws + 21397504);
    float* Sbuf  = ws + 22970368;
    float* Pbuf  = ws + 25067520;
    float* Cin   = ws + 27164672;
    f16*  pY     = (f16*)(ws + 29261824);

    prep_all<<<8512, 256, 0, stream>>>(x, W_in, W_out, W_x, W_dt,
                                       xh, W_in_t, W_out_t, WxT, WdtT, REPN);

    gemm_sk_f16<128, 128, HID, 512><<<1024, 256, 0, stream>>>(
        xh, W_in_t, pA, 4096, 32, 16, REPN);

    conv_gate<<<(SEQ * 4096 / 8) / 256, 256, 0, stream>>>(pA, conv_w, conv_b, hh, gateh, REPN);

    hwx_mfma<<<256, 256, 0, stream>>>(hh, WxT, parts, REPN);
    reduce_partials<<<(SEQ * NP / 8) / 256, 256, 0, stream>>>(parts, ssm_p, tsh, REPN);

    dt_mfma<<<256, 256, 0, stream>>>(tsh, WdtT, b_dt, dtbh, REPN);

    ssm_pass1<<<dim3(INTER / 256, NC), 256, 0, stream>>>(dtbh, hh, ssm_p, A_log, Sbuf, Pbuf, REPN);
    ssm_pass2<<<(INTER * DST) / 256, 256, 0, stream>>>(Sbuf, Pbuf, Cin, REPN);
    ssm_pass3<<<dim3(INTER / 256, NC), 256, 0, stream>>>(dtbh, hh, ssm_p, gateh, A_log, Dv, Cin, yh, REPN);

    gemm_sk_f16<64, 128, INTER, 1024><<<512, 256, 0, stream>>>(
        yh, W_out_t, pY, HID, 8, 32, REPN);
    reduce_out<<<(SEQ * HID / 8) / 256, 256, 0, stream>>>(pY, out, REPN);
}

// Round 11
// 514.520 us; speedup vs baseline: 2.0657x; 2.0657x over previous
//
#include <hip/hip_runtime.h>
#include <hip/hip_cooperative_groups.h>
#include <math.h>

namespace cg = cooperative_groups;

#define SEQ   2048
#define HID   1024
#define INTER 2048
#define DST   16
#define DTR   64
#define NP    96   // DTR + 2*DST
#define NC    64   // scan chunks
#define LCH   32   // steps per chunk (NC*LCH == SEQ)
#define KS    16   // split-K factor for h @ W_x

typedef _Float16 f16;
typedef _Float16 f16x8 __attribute__((ext_vector_type(8)));
typedef _Float16 f16x4v __attribute__((ext_vector_type(4)));
typedef float f32x4 __attribute__((ext_vector_type(4)));

__device__ __forceinline__ float sigmoidf_(float x) { return 1.0f / (1.0f + expf(-x)); }
__device__ __forceinline__ float siluf_(float x)    { return x * sigmoidf_(x); }
__device__ __forceinline__ float softplusf_(float x){ return (x > 20.0f) ? x : log1pf(expf(x)); }

struct MegaArgs {
    const float* x; const float* W_in; const float* W_out; const float* W_x; const float* W_dt;
    const float* conv_w; const float* conv_b; const float* b_dt; const float* A_log; const float* Dv;
    float* out;
    f16* xh; f16* W_in_t; f16* W_out_t; f16* WxT; f16* WdtT;
    f16* projh; f16* hh; f16* dtbh; f16* yh; f16* tsh; f16* parts;
    float* ssm_p; float* Sbuf; float* Pbuf; float* Cin;
};

// ---------------------------------------------------------------------------
// 32x32 tile transpose f32 -> f16^T through LDS scratch t[32][33]
// ---------------------------------------------------------------------------
__device__ __forceinline__ void tile_transpose(const float* __restrict__ W,
                                               f16* __restrict__ Wt,
                                               int K, int N, int bx, int by,
                                               int tid, float* t)
{
    const int n0 = bx * 32, k0 = by * 32;
    const int j = tid & 31, i0 = tid >> 5;   // i0: 0..7
    __syncthreads();                          // protect t across strided reuse
#pragma unroll
    for (int r = 0; r < 4; ++r)
        t[(i0 + r * 8) * 33 + j] = W[(size_t)(k0 + i0 + r * 8) * N + n0 + j];
    __syncthreads();
#pragma unroll
    for (int r = 0; r < 4; ++r)
        Wt[(size_t)(n0 + i0 + r * 8) * K + k0 + j] = (f16)t[j * 33 + i0 + r * 8];
}

// ---------------------------------------------------------------------------
// Phase: prep (virtual blocks 0..8512)
// ---------------------------------------------------------------------------
__device__ __forceinline__ void phase_prep(const MegaArgs& a, int v, int tid, float* t)
{
    if (v < 2048) {
        int i = (v * 256 + tid) * 4;
        float4 w = *(const float4*)&a.x[i];
        f16x4v o;
        o.x = (f16)w.x; o.y = (f16)w.y; o.z = (f16)w.z; o.w = (f16)w.w;
        *(f16x4v*)&a.xh[i] = o;
    } else if (v < 6144) {
        int q = v - 2048;                       // W_in: K=1024, N=4096
        tile_transpose(a.W_in, a.W_in_t, HID, 4096, q & 127, q >> 7, tid, t);
    } else if (v < 8192) {
        int q = v - 6144;                       // W_out: K=2048, N=1024
        tile_transpose(a.W_out, a.W_out_t, INTER, HID, q & 31, q >> 5, tid, t);
    } else if (v < 8384) {
        int q = v - 8192;                       // W_x: K=2048, N=96
        tile_transpose(a.W_x, a.WxT, INTER, NP, q % 3, q / 3, tid, t);
    } else {
        int q = v - 8384;                       // W_dt: K=64, N=2048
        tile_transpose(a.W_dt, a.WdtT, DTR, INTER, q & 63, q >> 6, tid, t);
    }
}

// ---------------------------------------------------------------------------
// m97-structure MFMA f16 GEMM tile: C[M,N] OutT = Ah[M,KTOT] @ Bt[N,KTOT]^T
// ---------------------------------------------------------------------------
template<int BM, int BN, int KTOT, typename OutT>
__device__ __forceinline__ void gemm_tile(const f16* __restrict__ Ah,
                                          const f16* __restrict__ Bt,
                                          OutT* __restrict__ C, int N,
                                          int bx, int by, int tid,
                                          f16* As, f16* Bs)
{
    constexpr int BK = 64;
    const int wid = tid >> 6, lane = tid & 63;
    const int wr = wid >> 1, wc = wid & 1;
    const int m0 = by * BM, n0 = bx * BN;
    const int l15 = lane & 15, lhi = lane >> 4;
    constexpr int MR = BM / 32;
    constexpr int NR = BN / 32;

    f32x4 acc[MR][NR] = {};

    for (int k0 = 0; k0 < KTOT; k0 += BK) {
        constexpr int CA = BM * BK * 2 / 1024;
#pragma unroll
        for (int c0 = 0; c0 < CA; c0 += 4) {
            int c = c0 + wid;
            int e = c * 64 + lane;
            int row = e >> 3, seg = e & 7;
            __builtin_amdgcn_global_load_lds(
                (const __attribute__((address_space(1))) unsigned int*)
                    (Ah + (size_t)(m0 + row) * KTOT + k0 + seg * 8),
                (__attribute__((address_space(3))) unsigned int*)(As + c * 512),
                16, 0, 0);
        }
        constexpr int CB = BN * BK * 2 / 1024;
#pragma unroll
        for (int c0 = 0; c0 < CB; c0 += 4) {
            int c = c0 + wid;
            int e = c * 64 + lane;
            int row = e >> 3, seg = e & 7;
            __builtin_amdgcn_global_load_lds(
                (const __attribute__((address_space(1))) unsigned int*)
                    (Bt + (size_t)(n0 + row) * KTOT + k0 + seg * 8),
                (__attribute__((address_space(3))) unsigned int*)(Bs + c * 512),
                16, 0, 0);
        }
        __syncthreads();

#pragma unroll
        for (int kk = 0; kk < BK; kk += 32) {
            f16x8 af[MR], bf[NR];
#pragma unroll
            for (int i = 0; i < MR; ++i)
                af[i] = *(const f16x8*)&As[(wr * (BM / 2) + i * 16 + l15) * BK + kk + lhi * 8];
#pragma unroll
            for (int n = 0; n < NR; ++n)
                bf[n] = *(const f16x8*)&Bs[(wc * (BN / 2) + n * 16 + l15) * BK + kk + lhi * 8];
#pragma unroll
            for (int i = 0; i < MR; ++i)
#pragma unroll
                for (int n = 0; n < NR; ++n)
                    acc[i][n] = __builtin_amdgcn_mfma_f32_16x16x32_f16(af[i], bf[n], acc[i][n], 0, 0, 0);
        }
        __syncthreads();
    }

    // C/D map: col = lane&15, row = (lane>>4)*4 + reg
#pragma unroll
    for (int i = 0; i < MR; ++i)
#pragma unroll
        for (int n = 0; n < NR; ++n)
#pragma unroll
            for (int r = 0; r < 4; ++r)
                C[(size_t)(m0 + wr * (BM / 2) + i * 16 + lhi * 4 + r) * N
                  + n0 + wc * (BN / 2) + n * 16 + l15] = (OutT)acc[i][n][r];
}

// ---------------------------------------------------------------------------
// Phase: conv+silu -> hh (virtual blocks 0..2048); gate stays in projh
// ---------------------------------------------------------------------------
__device__ __forceinline__ void phase_conv(const MegaArgs& a, int v, int tid)
{
    int idx = v * 256 + tid;
    int col = (idx & (INTER / 8 - 1)) * 8;
    int s = idx >> 8;
    float acc[8];
#pragma unroll
    for (int j = 0; j < 8; ++j) acc[j] = a.conv_b[col + j];
#pragma unroll
    for (int k = 0; k < 4; ++k) {
        int sp = s + k - 3;
        if (sp >= 0) {
            f16x8 p = *(const f16x8*)&a.projh[(size_t)sp * 4096 + col];
#pragma unroll
            for (int j = 0; j < 8; ++j)
                acc[j] = fmaf((float)p[j], a.conv_w[k * INTER + col + j], acc[j]);
        }
    }
    f16x8 o;
#pragma unroll
    for (int j = 0; j < 8; ++j) o[j] = (f16)siluf_(acc[j]);
    *(f16x8*)&a.hh[(size_t)s * INTER + col] = o;
}

// ---------------------------------------------------------------------------
// Phase: hwx split-K=16 -> parts (virtual blocks 0..256)
// ---------------------------------------------------------------------------
__device__ __forceinline__ void phase_hwx(const MegaArgs& a, int v, int tid,
                                          f16* As, f16* Bs)
{
    constexpr int BM = 128, BN = 96, BK = 64;
    const int bxm = v & 15, ks = v >> 4;
    const int wid = tid >> 6, lane = tid & 63;
    const int wr = wid >> 1, wc = wid & 1;
    const int m0 = bxm * BM;
    const int l15 = lane & 15, lhi = lane >> 4;
    f32x4 acc[4][3] = {};

    for (int k0 = ks * 128; k0 < ks * 128 + 128; k0 += BK) {
#pragma unroll
        for (int c0 = 0; c0 < 16; c0 += 4) {
            int c = c0 + wid;
            int e = c * 64 + lane;
            int row = e >> 3, seg = e & 7;
            __builtin_amdgcn_global_load_lds(
                (const __attribute__((address_space(1))) unsigned int*)
                    (a.hh + (size_t)(m0 + row) * INTER + k0 + seg * 8),
                (__attribute__((address_space(3))) unsigned int*)(As + c * 512),
                16, 0, 0);
        }
#pragma unroll
        for (int c0 = 0; c0 < 12; c0 += 4) {
            int c = c0 + wid;
            int e = c * 64 + lane;
            int row = e >> 3, seg = e & 7;
            __builtin_amdgcn_global_load_lds(
                (const __attribute__((address_space(1))) unsigned int*)
                    (a.WxT + (size_t)row * INTER + k0 + seg * 8),
                (__attribute__((address_space(3))) unsigned int*)(Bs + c * 512),
                16, 0, 0);
        }
        __syncthreads();

#pragma unroll
        for (int kk = 0; kk < BK; kk += 32) {
            f16x8 af[4], bf[3];
#pragma unroll
            for (int i = 0; i < 4; ++i)
                af[i] = *(const f16x8*)&As[(wr * 64 + i * 16 + l15) * BK + kk + lhi * 8];
#pragma unroll
            for (int n = 0; n < 3; ++n)
                bf[n] = *(const f16x8*)&Bs[(wc * 48 + n * 16 + l15) * BK + kk + lhi * 8];
#pragma unroll
            for (int i = 0; i < 4; ++i)
#pragma unroll
                for (int n = 0; n < 3; ++n)
                    acc[i][n] = __builtin_amdgcn_mfma_f32_16x16x32_f16(af[i], bf[n], acc[i][n], 0, 0, 0);
        }
        __syncthreads();
    }

    f16* P = a.parts + (size_t)ks * (SEQ * NP);
#pragma unroll
    for (int i = 0; i < 4; ++i)
#pragma unroll
        for (int n = 0; n < 3; ++n)
#pragma unroll
            for (int r = 0; r < 4; ++r)
                P[(size_t)(m0 + wr * 64 + i * 16 + lhi * 4 + r) * NP
                  + wc * 48 + n * 16 + l15] = (f16)acc[i][n][r];
}

// ---------------------------------------------------------------------------
// Phase: reduce parts -> ssm_p (B,C) + tsh (virtual blocks 0..96)
// ---------------------------------------------------------------------------
__device__ __forceinline__ void phase_reduce(const MegaArgs& a, int v, int tid)
{
    int i8 = (v * 256 + tid) * 8;
    int s = i8 / NP, j0 = i8 % NP;
    float acc[8] = {};
#pragma unroll
    for (int c = 0; c < KS; ++c) {
        f16x8 w = *(const f16x8*)&a.parts[(size_t)c * (SEQ * NP) + i8];
#pragma unroll
        for (int j = 0; j < 8; ++j) acc[j] += (float)w[j];
    }
    if (j0 < DTR) {
        f16x8 o;
#pragma unroll
        for (int j = 0; j < 8; ++j) o[j] = (f16)acc[j];
        *(f16x8*)&a.tsh[(size_t)s * DTR + j0] = o;
    } else {
        *(float4*)&a.ssm_p[(size_t)s * NP + j0]     = make_float4(acc[0], acc[1], acc[2], acc[3]);
        *(float4*)&a.ssm_p[(size_t)s * NP + j0 + 4] = make_float4(acc[4], acc[5], acc[6], acc[7]);
    }
}

// ---------------------------------------------------------------------------
// Phase: dt = softplus(ts @ W_dt + b_dt) (virtual blocks 0..256)
// ---------------------------------------------------------------------------
__device__ __forceinline__ void phase_dt(const MegaArgs& a, int v, int tid,
                                         f16* As, f16* Bs)
{
    constexpr int BK = 64;
    const int bx = v & 15, by = v >> 4;
    const int wid = tid >> 6, lane = tid & 63;
    const int wr = wid >> 1, wc = wid & 1;
    const int m0 = by * 128, n0 = bx * 128;
    const int l15 = lane & 15, lhi = lane >> 4;
    f32x4 acc[4][4] = {};

#pragma unroll
    for (int c0 = 0; c0 < 16; c0 += 4) {
        int c = c0 + wid;
        int e = c * 64 + lane;
        int row = e >> 3, seg = e & 7;
        __builtin_amdgcn_global_load_lds(
            (const __attribute__((address_space(1))) unsigned int*)
                (a.tsh + (size_t)(m0 + row) * DTR + seg * 8),
            (__attribute__((address_space(3))) unsigned int*)(As + c * 512),
            16, 0, 0);
        __builtin_amdgcn_global_load_lds(
            (const __attribute__((address_space(1))) unsigned int*)
                (a.WdtT + (size_t)(n0 + row) * DTR + seg * 8),
            (__attribute__((address_space(3))) unsigned int*)(Bs + c * 512),
            16, 0, 0);
    }
    __syncthreads();

#pragma unroll
    for (int kk = 0; kk < 64; kk += 32) {
        f16x8 af[4], bf[4];
#pragma unroll
        for (int i = 0; i < 4; ++i)
            af[i] = *(const f16x8*)&As[(wr * 64 + i * 16 + l15) * BK + kk + lhi * 8];
#pragma unroll
        for (int n = 0; n < 4; ++n)
            bf[n] = *(const f16x8*)&Bs[(wc * 64 + n * 16 + l15) * BK + kk + lhi * 8];
#pragma unroll
        for (int i = 0; i < 4; ++i)
#pragma unroll
            for (int n = 0; n < 4; ++n)
                acc[i][n] = __builtin_amdgcn_mfma_f32_16x16x32_f16(af[i], bf[n], acc[i][n], 0, 0, 0);
    }

#pragma unroll
    for (int i = 0; i < 4; ++i)
#pragma unroll
        for (int n = 0; n < 4; ++n) {
            int col = n0 + wc * 64 + n * 16 + l15;
            float bv = a.b_dt[col];
#pragma unroll
            for (int r = 0; r < 4; ++r)
                a.dtbh[(size_t)(m0 + wr * 64 + i * 16 + lhi * 4 + r) * INTER + col] =
                    (f16)softplusf_(acc[i][n][r] + bv);
        }
    __syncthreads();
}

// ---------------------------------------------------------------------------
// Phase: scan pass1 (virtual blocks 0..512: 8 h-blocks x 64 chunks)
// ---------------------------------------------------------------------------
__device__ __forceinline__ void phase_pass1(const MegaArgs& a, int v, int tid, float* Bsc)
{
    const int hblk = v >> 6, c = v & 63;
    const int h = hblk * 256 + tid;
    const int s0 = c * LCH;
    for (int j = tid; j < LCH * DST; j += 256) {
        int r = j >> 4, dd = j & 15;
        Bsc[r * DST + dd] = a.ssm_p[(size_t)(s0 + r) * NP + DTR + dd];
    }
    __syncthreads();

    float A[DST], st[DST];
#pragma unroll
    for (int d = 0; d < DST; ++d) {
        A[d] = -__expf(a.A_log[(size_t)h * DST + d]);
        st[d] = 0.0f;
    }
    float dtsum = 0.0f;
    for (int r = 0; r < LCH; ++r) {
        float dtv = (float)a.dtbh[(size_t)(s0 + r) * INTER + h];
        float hv  = (float)a.hh[(size_t)(s0 + r) * INTER + h];
        float dh = dtv * hv;
        dtsum += dtv;
#pragma unroll
        for (int d = 0; d < DST; ++d) {
            float da = __expf(dtv * A[d]);
            st[d] = fmaf(da, st[d], dh * Bsc[r * DST + d]);
        }
    }
    size_t base = ((size_t)c * INTER + h) * DST;
#pragma unroll
    for (int d = 0; d < DST; d += 4) {
        *(float4*)&a.Sbuf[base + d] = make_float4(st[d], st[d+1], st[d+2], st[d+3]);
        float4 p4;
        p4.x = __expf(A[d]     * dtsum);
        p4.y = __expf(A[d + 1] * dtsum);
        p4.z = __expf(A[d + 2] * dtsum);
        p4.w = __expf(A[d + 3] * dtsum);
        *(float4*)&a.Pbuf[base + d] = p4;
    }
    __syncthreads();
}

__device__ __forceinline__ void phase_pass2(const MegaArgs& a, int v, int tid)
{
    int i = v * 256 + tid;
    float carry = 0.0f;
#pragma unroll 8
    for (int c = 0; c < NC; ++c) {
        size_t idx = (size_t)c * (INTER * DST) + i;
        a.Cin[idx] = carry;
        carry = fmaf(a.Pbuf[idx], carry, a.Sbuf[idx]);
    }
}

__device__ __forceinline__ void phase_pass3(const MegaArgs& a, int v, int tid, float* Bsc)
{
    float* Csc = Bsc + LCH * DST;
    const int hblk = v >> 6, c = v & 63;
    const int h = hblk * 256 + tid;
    const int s0 = c * LCH;
    for (int j = tid; j < LCH * DST; j += 256) {
        int r = j >> 4, dd = j & 15;
        Bsc[r * DST + dd] = a.ssm_p[(size_t)(s0 + r) * NP + DTR + dd];
        Csc[r * DST + dd] = a.ssm_p[(size_t)(s0 + r) * NP + DTR + DST + dd];
    }
    __syncthreads();

    float A[DST], st[DST];
    size_t base = ((size_t)c * INTER + h) * DST;
#pragma unroll
    for (int d = 0; d < DST; ++d) {
        A[d] = -__expf(a.A_log[(size_t)h * DST + d]);
        st[d] = a.Cin[base + d];
    }
    const float Dvv = a.Dv[h];

    for (int r = 0; r < LCH; ++r) {
        float dtv = (float)a.dtbh[(size_t)(s0 + r) * INTER + h];
        float hv  = (float)a.hh[(size_t)(s0 + r) * INTER + h];
        float g   = (float)a.projh[(size_t)(s0 + r) * 4096 + INTER + h];
        float dh = dtv * hv;
        float y = 0.0f;
#pragma unroll
        for (int d = 0; d < DST; ++d) {
            float da = __expf(dtv * A[d]);
            st[d] = fmaf(da, st[d], dh * Bsc[r * DST + d]);
            y = fmaf(st[d], Csc[r * DST + d], y);
        }
        y = fmaf(hv, Dvv, y);
        a.yh[(size_t)(s0 + r) * INTER + h] = (f16)(y * siluf_(g));
    }
    __syncthreads();
}

// ---------------------------------------------------------------------------
// Cooperative mega-kernel: 10 phases, 9 grid syncs, works for any grid size.
// ---------------------------------------------------------------------------
__global__ __launch_bounds__(256, 2) void mega(MegaArgs a)
{
    cg::grid_group grid = cg::this_grid();
    const int bid = blockIdx.x, tid = threadIdx.x;
    const int G = gridDim.x;
    __shared__ __align__(16) unsigned char smem[32768];

    for (int v = bid; v < 8512; v += G) phase_prep(a, v, tid, (float*)smem);
    grid.sync();
    for (int v = bid; v < 512; v += G)
        gemm_tile<128, 128, HID, f16>(a.xh, a.W_in_t, a.projh, 4096,
                                      v % 32, v / 32, tid,
                                      (f16*)smem, (f16*)(smem + 16384));
    grid.sync();
    for (int v = bid; v < 2048; v += G) phase_conv(a, v, tid);
    grid.sync();
    for (int v = bid; v < 256; v += G)
        phase_hwx(a, v, tid, (f16*)smem, (f16*)(smem + 16384));
    grid.sync();
    for (int v = bid; v < 96; v += G) phase_reduce(a, v, tid);
    grid.sync();
    for (int v = bid; v < 256; v += G)
        phase_dt(a, v, tid, (f16*)smem, (f16*)(smem + 16384));
    grid.sync();
    for (int v = bid; v < 512; v += G) phase_pass1(a, v, tid, (float*)smem);
    grid.sync();
    for (int v = bid; v < 128; v += G) phase_pass2(a, v, tid);
    grid.sync();
    for (int v = bid; v < 512; v += G) phase_pass3(a, v, tid, (float*)smem);
    grid.sync();
    for (int v = bid; v < 256; v += G)
        gemm_tile<64, 128, INTER, float>(a.yh, a.W_out_t, a.out, HID,
                                         v & 7, v >> 3, tid,
                                         (f16*)smem, (f16*)(smem + 8192));
}

// ---------------------------------------------------------------------------
// Fallback wrappers (exact grids, own LDS sizes)
// ---------------------------------------------------------------------------
__global__ __launch_bounds__(256) void k_prep(MegaArgs a)
{
    __shared__ float t[32 * 33];
    phase_prep(a, blockIdx.x, threadIdx.x, t);
}
__global__ __launch_bounds__(256) void k_gemm1(MegaArgs a)
{
    __shared__ __align__(16) f16 As[128 * 64];
    __shared__ __align__(16) f16 Bs[128 * 64];
    gemm_tile<128, 128, HID, f16>(a.xh, a.W_in_t, a.projh, 4096,
                                  (int)blockIdx.x % 32, (int)blockIdx.x / 32,
                                  threadIdx.x, As, Bs);
}
__global__ __launch_bounds__(256) void k_conv(MegaArgs a)
{
    phase_conv(a, blockIdx.x, threadIdx.x);
}
__global__ __launch_bounds__(256) void k_hwx(MegaArgs a)
{
    __shared__ __align__(16) f16 As[128 * 64];
    __shared__ __align__(16) f16 Bs[96 * 64];
    phase_hwx(a, blockIdx.x, threadIdx.x, As, Bs);
}
__global__ __launch_bounds__(256) void k_reduce(MegaArgs a)
{
    phase_reduce(a, blockIdx.x, threadIdx.x);
}
__global__ __launch_bounds__(256) void k_dt(MegaArgs a)
{
    __shared__ __align__(16) f16 As[128 * 64];
    __shared__ __align__(16) f16 Bs[128 * 64];
    phase_dt(a, blockIdx.x, threadIdx.x, As, Bs);
}
__global__ __launch_bounds__(256) void k_pass1(MegaArgs a)
{
    __shared__ float b[LCH * DST];
    phase_pass1(a, blockIdx.x, threadIdx.x, b);
}
__global__ __launch_bounds__(256) void k_pass2(MegaArgs a)
{
    phase_pass2(a, blockIdx.x, threadIdx.x);
}
__global__ __launch_bounds__(256) void k_pass3(MegaArgs a)
{
    __shared__ float b[2 * LCH * DST];
    phase_pass3(a, blockIdx.x, threadIdx.x, b);
}
__global__ __launch_bounds__(256) void k_gemm2(MegaArgs a)
{
    __shared__ __align__(16) f16 As[64 * 64];
    __shared__ __align__(16) f16 Bs[128 * 64];
    gemm_tile<64, 128, INTER, float>(a.yh, a.W_out_t, a.out, HID,
                                     (int)blockIdx.x & 7, (int)blockIdx.x >> 3,
                                     threadIdx.x, As, Bs);
}

// ---------------------------------------------------------------------------
extern "C" void kernel_launch(void* const* d_in, const int* in_sizes, int n_in,
                              void* d_out, int out_size, void* d_ws, size_t ws_size,
                              hipStream_t stream)
{
    float* ws = (float*)d_ws;
    MegaArgs a;
    a.x      = (const float*)d_in[0];
    a.W_in   = (const float*)d_in[1];
    a.conv_w = (const float*)d_in[2];
    a.conv_b = (const float*)d_in[3];
    a.W_x    = (const float*)d_in[4];
    a.W_dt   = (const float*)d_in[5];
    a.b_dt   = (const float*)d_in[6];
    a.A_log  = (const float*)d_in[7];
    a.Dv     = (const float*)d_in[8];
    a.W_out  = (const float*)d_in[9];
    a.out    = (float*)d_out;

    a.projh  = (f16*)ws;
    a.hh     = (f16*)(ws + 4194304);
    a.dtbh   = (f16*)(ws + 6291456);
    a.yh     = (f16*)(ws + 8388608);
    a.xh     = (f16*)(ws + 10485760);
    a.W_in_t = (f16*)(ws + 11534336);
    a.W_out_t= (f16*)(ws + 13631488);
    a.WxT    = (f16*)(ws + 14680064);
    a.tsh    = (f16*)(ws + 14778368);
    a.WdtT   = (f16*)(ws + 14843904);
    a.ssm_p  = ws + 14909440;
    a.parts  = (f16*)(ws + 15106048);
    a.Sbuf   = ws + 16678912;
    a.Pbuf   = ws + 18776064;
    a.Cin    = ws + 20873216;

    // --- decide coop vs multi-launch (host-side, deterministic, capture-safe)
    bool coop_ok = false;
    int dev = 0;
    if (hipGetDevice(&dev) == hipSuccess) {
        int attr = 0, ncu = 0, maxb = 0;
        hipDeviceGetAttribute(&attr, hipDeviceAttributeCooperativeLaunch, dev);
        hipDeviceGetAttribute(&ncu, hipDeviceAttributeMultiprocessorCount, dev);
        hipError_t oe = hipOccupancyMaxActiveBlocksPerMultiprocessor(&maxb, mega, 256, 0);
        if (attr && oe == hipSuccess && maxb > 0 && ncu > 0) {
            int grid = maxb * ncu;
            if (grid > 512) grid = 512;
            if (grid >= 256) {
                void* params[] = { (void*)&a };
                hipError_t e = hipLaunchCooperativeKernel((const void*)mega,
                                                          dim3(grid), dim3(256),
                                                          params, 0, stream);
                if (e == hipSuccess) coop_ok = true;
                else (void)hipGetLastError();   // clear, fall through
            }
        }
    }

    if (!coop_ok) {
        k_prep  <<<8512, 256, 0, stream>>>(a);
        k_gemm1 <<<512,  256, 0, stream>>>(a);
        k_conv  <<<2048, 256, 0, stream>>>(a);
        k_hwx   <<<256,  256, 0, stream>>>(a);
        k_reduce<<<96,   256, 0, stream>>>(a);
        k_dt    <<<256,  256, 0, stream>>>(a);
        k_pass1 <<<512,  256, 0, stream>>>(a);
        k_pass2 <<<128,  256, 0, stream>>>(a);
        k_pass3 <<<512,  256, 0, stream>>>(a);
        k_gemm2 <<<256,  256, 0, stream>>>(a);
    }
}

// Round 12
// 191.031 us; speedup vs baseline: 5.5637x; 2.6934x over previous
//
#include <hip/hip_runtime.h>
#include <math.h>

#define SEQ   2048
#define HID   1024
#define INTER 2048
#define DST   16
#define DTR   64
#define NP    96   // DTR + 2*DST
#define NC    64   // scan chunks
#define LCH   32   // steps per chunk (NC*LCH == SEQ)
#define KS    16   // split-K factor for h @ W_x

typedef _Float16 f16;
typedef _Float16 f16x8 __attribute__((ext_vector_type(8)));
typedef _Float16 f16x4v __attribute__((ext_vector_type(4)));
typedef float f32x4 __attribute__((ext_vector_type(4)));

__device__ __forceinline__ float sigmoidf_(float x) { return 1.0f / (1.0f + expf(-x)); }
__device__ __forceinline__ float siluf_(float x)    { return x * sigmoidf_(x); }
__device__ __forceinline__ float softplusf_(float x){ return (x > 20.0f) ? x : log1pf(expf(x)); }

struct Args {
    const float* x; const float* W_in; const float* W_out; const float* W_x; const float* W_dt;
    const float* conv_w; const float* conv_b; const float* b_dt; const float* A_log; const float* Dv;
    float* out;
    f16* xh; f16* W_in_t; f16* W_out_t; f16* WxT; f16* WdtT;
    f16* projh; f16* hh; f16* dtbh; f16* yh; f16* tsh; f16* parts;
    float* ssm_p; float* Sbuf; float* Pbuf; float* Cin;
};

// ---------------------------------------------------------------------------
// 32x32 tile transpose f32 -> f16^T through LDS scratch t[32][33]
// ---------------------------------------------------------------------------
__device__ __forceinline__ void tile_transpose(const float* __restrict__ W,
                                               f16* __restrict__ Wt,
                                               int K, int N, int bx, int by,
                                               int tid, float* t)
{
    const int n0 = bx * 32, k0 = by * 32;
    const int j = tid & 31, i0 = tid >> 5;   // i0: 0..7
#pragma unroll
    for (int r = 0; r < 4; ++r)
        t[(i0 + r * 8) * 33 + j] = W[(size_t)(k0 + i0 + r * 8) * N + n0 + j];
    __syncthreads();
#pragma unroll
    for (int r = 0; r < 4; ++r)
        Wt[(size_t)(n0 + i0 + r * 8) * K + k0 + j] = (f16)t[j * 33 + i0 + r * 8];
}

// ---------------------------------------------------------------------------
// m97-structure MFMA f16 GEMM tile: C[M,N] OutT = Ah[M,KTOT] @ Bt[N,KTOT]^T
// ---------------------------------------------------------------------------
template<int BM, int BN, int KTOT, typename OutT>
__device__ __forceinline__ void gemm_tile(const f16* __restrict__ Ah,
                                          const f16* __restrict__ Bt,
                                          OutT* __restrict__ C, int N,
                                          int bx, int by, int tid,
                                          f16* As, f16* Bs)
{
    constexpr int BK = 64;
    const int wid = tid >> 6, lane = tid & 63;
    const int wr = wid >> 1, wc = wid & 1;
    const int m0 = by * BM, n0 = bx * BN;
    const int l15 = lane & 15, lhi = lane >> 4;
    constexpr int MR = BM / 32;
    constexpr int NR = BN / 32;

    f32x4 acc[MR][NR] = {};

    for (int k0 = 0; k0 < KTOT; k0 += BK) {
        constexpr int CA = BM * BK * 2 / 1024;
#pragma unroll
        for (int c0 = 0; c0 < CA; c0 += 4) {
            int c = c0 + wid;
            int e = c * 64 + lane;
            int row = e >> 3, seg = e & 7;
            __builtin_amdgcn_global_load_lds(
                (const __attribute__((address_space(1))) unsigned int*)
                    (Ah + (size_t)(m0 + row) * KTOT + k0 + seg * 8),
                (__attribute__((address_space(3))) unsigned int*)(As + c * 512),
                16, 0, 0);
        }
        constexpr int CB = BN * BK * 2 / 1024;
#pragma unroll
        for (int c0 = 0; c0 < CB; c0 += 4) {
            int c = c0 + wid;
            int e = c * 64 + lane;
            int row = e >> 3, seg = e & 7;
            __builtin_amdgcn_global_load_lds(
                (const __attribute__((address_space(1))) unsigned int*)
                    (Bt + (size_t)(n0 + row) * KTOT + k0 + seg * 8),
                (__attribute__((address_space(3))) unsigned int*)(Bs + c * 512),
                16, 0, 0);
        }
        __syncthreads();

#pragma unroll
        for (int kk = 0; kk < BK; kk += 32) {
            f16x8 af[MR], bf[NR];
#pragma unroll
            for (int i = 0; i < MR; ++i)
                af[i] = *(const f16x8*)&As[(wr * (BM / 2) + i * 16 + l15) * BK + kk + lhi * 8];
#pragma unroll
            for (int n = 0; n < NR; ++n)
                bf[n] = *(const f16x8*)&Bs[(wc * (BN / 2) + n * 16 + l15) * BK + kk + lhi * 8];
#pragma unroll
            for (int i = 0; i < MR; ++i)
#pragma unroll
                for (int n = 0; n < NR; ++n)
                    acc[i][n] = __builtin_amdgcn_mfma_f32_16x16x32_f16(af[i], bf[n], acc[i][n], 0, 0, 0);
        }
        __syncthreads();
    }

    // C/D map: col = lane&15, row = (lane>>4)*4 + reg
#pragma unroll
    for (int i = 0; i < MR; ++i)
#pragma unroll
        for (int n = 0; n < NR; ++n)
#pragma unroll
            for (int r = 0; r < 4; ++r)
                C[(size_t)(m0 + wr * (BM / 2) + i * 16 + lhi * 4 + r) * N
                  + n0 + wc * (BN / 2) + n * 16 + l15] = (OutT)acc[i][n][r];
}

// ---------------------------------------------------------------------------
// L1: x->f16 + W_in transpose (6144 blocks)
// ---------------------------------------------------------------------------
__global__ __launch_bounds__(256) void k_prep_a(Args a)
{
    __shared__ float t[32 * 33];
    const int v = blockIdx.x, tid = threadIdx.x;
    if (v < 2048) {
        int i = (v * 256 + tid) * 4;
        float4 w = *(const float4*)&a.x[i];
        f16x4v o;
        o.x = (f16)w.x; o.y = (f16)w.y; o.z = (f16)w.z; o.w = (f16)w.w;
        *(f16x4v*)&a.xh[i] = o;
    } else {
        int q = v - 2048;                       // W_in: K=1024, N=4096
        tile_transpose(a.W_in, a.W_in_t, HID, 4096, q & 127, q >> 7, tid, t);
    }
}

// ---------------------------------------------------------------------------
// L2: gemm1 (512 tiles) + rider transposes for W_out / W_x / W_dt (2368)
// ---------------------------------------------------------------------------
__global__ __launch_bounds__(256) void k_gemm1r(Args a)
{
    __shared__ __align__(16) unsigned char smem[32768];
    const int v = blockIdx.x, tid = threadIdx.x;
    if (v < 512) {
        gemm_tile<128, 128, HID, f16>(a.xh, a.W_in_t, a.projh, 4096,
                                      v % 32, v / 32, tid,
                                      (f16*)smem, (f16*)(smem + 16384));
    } else {
        float* t = (float*)smem;
        int q = v - 512;
        if (q < 2048) {                         // W_out: K=2048, N=1024
            tile_transpose(a.W_out, a.W_out_t, INTER, HID, q & 31, q >> 5, tid, t);
        } else if (q < 2240) {                  // W_x: K=2048, N=96
            int r = q - 2048;
            tile_transpose(a.W_x, a.WxT, INTER, NP, r % 3, r / 3, tid, t);
        } else {                                // W_dt: K=64, N=2048
            int r = q - 2240;
            tile_transpose(a.W_dt, a.WdtT, DTR, INTER, r & 63, r >> 6, tid, t);
        }
    }
}

// ---------------------------------------------------------------------------
// L3: fused conv+silu into hwx A-staging; writes hh as byproduct.
// Each block (bxm, ks) computes its 128x128 h-tile exactly once.
// ---------------------------------------------------------------------------
__global__ __launch_bounds__(256) void k_hwxc(Args a)
{
    constexpr int BM = 128, BN = 96, BK = 64;
    __shared__ __align__(16) f16 As[BM * BK];
    __shared__ __align__(16) f16 Bs[BN * BK];

    const int v = blockIdx.x;
    const int bxm = v & 15, ks = v >> 4;
    const int tid = threadIdx.x;
    const int wid = tid >> 6, lane = tid & 63;
    const int wr = wid >> 1, wc = wid & 1;
    const int m0 = bxm * BM;
    const int l15 = lane & 15, lhi = lane >> 4;

    f32x4 acc[4][3] = {};

    for (int k0 = ks * 128; k0 < ks * 128 + 128; k0 += BK) {
        // B staging via global_load_lds (unchanged)
#pragma unroll
        for (int c0 = 0; c0 < 12; c0 += 4) {
            int c = c0 + wid;
            int e = c * 64 + lane;
            int row = e >> 3, seg = e & 7;
            __builtin_amdgcn_global_load_lds(
                (const __attribute__((address_space(1))) unsigned int*)
                    (a.WxT + (size_t)row * INTER + k0 + seg * 8),
                (__attribute__((address_space(3))) unsigned int*)(Bs + c * 512),
                16, 0, 0);
        }
        // A staging: conv+silu computed in registers, ds_write + hh store.
        // 1024 16B-units (128 rows x 8 segs), 4 per thread.
#pragma unroll
        for (int i = 0; i < 4; ++i) {
            int u = tid + i * 256;
            int row = u >> 3, seg = u & 7;
            int s = m0 + row;
            int c8 = k0 + seg * 8;
            float av[8];
#pragma unroll
            for (int j = 0; j < 8; ++j) av[j] = a.conv_b[c8 + j];
#pragma unroll
            for (int k = 0; k < 4; ++k) {
                int sp = s + k - 3;
                if (sp >= 0) {
                    f16x8 p = *(const f16x8*)&a.projh[(size_t)sp * 4096 + c8];
#pragma unroll
                    for (int j = 0; j < 8; ++j)
                        av[j] = fmaf((float)p[j], a.conv_w[k * INTER + c8 + j], av[j]);
                }
            }
            f16x8 o;
#pragma unroll
            for (int j = 0; j < 8; ++j) o[j] = (f16)siluf_(av[j]);
            *(f16x8*)&As[row * 64 + seg * 8] = o;
            *(f16x8*)&a.hh[(size_t)s * INTER + c8] = o;
        }
        __syncthreads();

#pragma unroll
        for (int kk = 0; kk < BK; kk += 32) {
            f16x8 af[4], bf[3];
#pragma unroll
            for (int i = 0; i < 4; ++i)
                af[i] = *(const f16x8*)&As[(wr * 64 + i * 16 + l15) * BK + kk + lhi * 8];
#pragma unroll
            for (int n = 0; n < 3; ++n)
                bf[n] = *(const f16x8*)&Bs[(wc * 48 + n * 16 + l15) * BK + kk + lhi * 8];
#pragma unroll
            for (int i = 0; i < 4; ++i)
#pragma unroll
                for (int n = 0; n < 3; ++n)
                    acc[i][n] = __builtin_amdgcn_mfma_f32_16x16x32_f16(af[i], bf[n], acc[i][n], 0, 0, 0);
        }
        __syncthreads();
    }

    f16* P = a.parts + (size_t)ks * (SEQ * NP);
#pragma unroll
    for (int i = 0; i < 4; ++i)
#pragma unroll
        for (int n = 0; n < 3; ++n)
#pragma unroll
            for (int r = 0; r < 4; ++r)
                P[(size_t)(m0 + wr * 64 + i * 16 + lhi * 4 + r) * NP
                  + wc * 48 + n * 16 + l15] = (f16)acc[i][n][r];
}

// ---------------------------------------------------------------------------
// L4: reduce 16 f16 planes -> ssm_p (B,C f32) + tsh (ts f16) (96 blocks)
// ---------------------------------------------------------------------------
__global__ __launch_bounds__(256) void k_reduce(Args a)
{
    int i8 = (blockIdx.x * 256 + threadIdx.x) * 8;
    int s = i8 / NP, j0 = i8 % NP;
    float acc[8] = {};
#pragma unroll
    for (int c = 0; c < KS; ++c) {
        f16x8 w = *(const f16x8*)&a.parts[(size_t)c * (SEQ * NP) + i8];
#pragma unroll
        for (int j = 0; j < 8; ++j) acc[j] += (float)w[j];
    }
    if (j0 < DTR) {
        f16x8 o;
#pragma unroll
        for (int j = 0; j < 8; ++j) o[j] = (f16)acc[j];
        *(f16x8*)&a.tsh[(size_t)s * DTR + j0] = o;
    } else {
        *(float4*)&a.ssm_p[(size_t)s * NP + j0]     = make_float4(acc[0], acc[1], acc[2], acc[3]);
        *(float4*)&a.ssm_p[(size_t)s * NP + j0 + 4] = make_float4(acc[4], acc[5], acc[6], acc[7]);
    }
}

// ---------------------------------------------------------------------------
// L5: dt = softplus(ts @ W_dt + b_dt) -> f16 (256 blocks)
// ---------------------------------------------------------------------------
__global__ __launch_bounds__(256) void k_dt(Args a)
{
    constexpr int BK = 64;
    __shared__ __align__(16) f16 As[128 * 64];
    __shared__ __align__(16) f16 Bs[128 * 64];
    const int v = blockIdx.x, tid = threadIdx.x;
    const int bx = v & 15, by = v >> 4;
    const int wid = tid >> 6, lane = tid & 63;
    const int wr = wid >> 1, wc = wid & 1;
    const int m0 = by * 128, n0 = bx * 128;
    const int l15 = lane & 15, lhi = lane >> 4;
    f32x4 acc[4][4] = {};

#pragma unroll
    for (int c0 = 0; c0 < 16; c0 += 4) {
        int c = c0 + wid;
        int e = c * 64 + lane;
        int row = e >> 3, seg = e & 7;
        __builtin_amdgcn_global_load_lds(
            (const __attribute__((address_space(1))) unsigned int*)
                (a.tsh + (size_t)(m0 + row) * DTR + seg * 8),
            (__attribute__((address_space(3))) unsigned int*)(As + c * 512),
            16, 0, 0);
        __builtin_amdgcn_global_load_lds(
            (const __attribute__((address_space(1))) unsigned int*)
                (a.WdtT + (size_t)(n0 + row) * DTR + seg * 8),
            (__attribute__((address_space(3))) unsigned int*)(Bs + c * 512),
            16, 0, 0);
    }
    __syncthreads();

#pragma unroll
    for (int kk = 0; kk < 64; kk += 32) {
        f16x8 af[4], bf[4];
#pragma unroll
        for (int i = 0; i < 4; ++i)
            af[i] = *(const f16x8*)&As[(wr * 64 + i * 16 + l15) * BK + kk + lhi * 8];
#pragma unroll
        for (int n = 0; n < 4; ++n)
            bf[n] = *(const f16x8*)&Bs[(wc * 64 + n * 16 + l15) * BK + kk + lhi * 8];
#pragma unroll
        for (int i = 0; i < 4; ++i)
#pragma unroll
            for (int n = 0; n < 4; ++n)
                acc[i][n] = __builtin_amdgcn_mfma_f32_16x16x32_f16(af[i], bf[n], acc[i][n], 0, 0, 0);
    }

#pragma unroll
    for (int i = 0; i < 4; ++i)
#pragma unroll
        for (int n = 0; n < 4; ++n) {
            int col = n0 + wc * 64 + n * 16 + l15;
            float bv = a.b_dt[col];
#pragma unroll
            for (int r = 0; r < 4; ++r)
                a.dtbh[(size_t)(m0 + wr * 64 + i * 16 + lhi * 4 + r) * INTER + col] =
                    (f16)softplusf_(acc[i][n][r] + bv);
        }
}

// ---------------------------------------------------------------------------
// L6-L8: chunked scan
// ---------------------------------------------------------------------------
__global__ __launch_bounds__(256) void k_pass1(Args a)
{
    __shared__ float Bsc[LCH * DST];
    const int v = blockIdx.x, tid = threadIdx.x;
    const int hblk = v >> 6, c = v & 63;
    const int h = hblk * 256 + tid;
    const int s0 = c * LCH;
    for (int j = tid; j < LCH * DST; j += 256) {
        int r = j >> 4, dd = j & 15;
        Bsc[r * DST + dd] = a.ssm_p[(size_t)(s0 + r) * NP + DTR + dd];
    }
    __syncthreads();

    float A[DST], st[DST];
#pragma unroll
    for (int d = 0; d < DST; ++d) {
        A[d] = -__expf(a.A_log[(size_t)h * DST + d]);
        st[d] = 0.0f;
    }
    float dtsum = 0.0f;
#pragma unroll 2
    for (int r = 0; r < LCH; ++r) {
        float dtv = (float)a.dtbh[(size_t)(s0 + r) * INTER + h];
        float hv  = (float)a.hh[(size_t)(s0 + r) * INTER + h];
        float dh = dtv * hv;
        dtsum += dtv;
#pragma unroll
        for (int d = 0; d < DST; ++d) {
            float da = __expf(dtv * A[d]);
            st[d] = fmaf(da, st[d], dh * Bsc[r * DST + d]);
        }
    }
    size_t base = ((size_t)c * INTER + h) * DST;
#pragma unroll
    for (int d = 0; d < DST; d += 4) {
        *(float4*)&a.Sbuf[base + d] = make_float4(st[d], st[d+1], st[d+2], st[d+3]);
        float4 p4;
        p4.x = __expf(A[d]     * dtsum);
        p4.y = __expf(A[d + 1] * dtsum);
        p4.z = __expf(A[d + 2] * dtsum);
        p4.w = __expf(A[d + 3] * dtsum);
        *(float4*)&a.Pbuf[base + d] = p4;
    }
}

__global__ __launch_bounds__(256) void k_pass2(Args a)
{
    int i = blockIdx.x * 256 + threadIdx.x;
    float carry = 0.0f;
#pragma unroll 8
    for (int c = 0; c < NC; ++c) {
        size_t idx = (size_t)c * (INTER * DST) + i;
        a.Cin[idx] = carry;
        carry = fmaf(a.Pbuf[idx], carry, a.Sbuf[idx]);
    }
}

__global__ __launch_bounds__(256) void k_pass3(Args a)
{
    __shared__ float Bsc[LCH * DST];
    __shared__ float Csc[LCH * DST];
    const int v = blockIdx.x, tid = threadIdx.x;
    const int hblk = v >> 6, c = v & 63;
    const int h = hblk * 256 + tid;
    const int s0 = c * LCH;
    for (int j = tid; j < LCH * DST; j += 256) {
        int r = j >> 4, dd = j & 15;
        Bsc[r * DST + dd] = a.ssm_p[(size_t)(s0 + r) * NP + DTR + dd];
        Csc[r * DST + dd] = a.ssm_p[(size_t)(s0 + r) * NP + DTR + DST + dd];
    }
    __syncthreads();

    float A[DST], st[DST];
    size_t base = ((size_t)c * INTER + h) * DST;
#pragma unroll
    for (int d = 0; d < DST; ++d) {
        A[d] = -__expf(a.A_log[(size_t)h * DST + d]);
        st[d] = a.Cin[base + d];
    }
    const float Dvv = a.Dv[h];

#pragma unroll 2
    for (int r = 0; r < LCH; ++r) {
        float dtv = (float)a.dtbh[(size_t)(s0 + r) * INTER + h];
        float hv  = (float)a.hh[(size_t)(s0 + r) * INTER + h];
        float g   = (float)a.projh[(size_t)(s0 + r) * 4096 + INTER + h];
        float dh = dtv * hv;
        float y = 0.0f;
#pragma unroll
        for (int d = 0; d < DST; ++d) {
            float da = __expf(dtv * A[d]);
            st[d] = fmaf(da, st[d], dh * Bsc[r * DST + d]);
            y = fmaf(st[d], Csc[r * DST + d], y);
        }
        y = fmaf(hv, Dvv, y);
        a.yh[(size_t)(s0 + r) * INTER + h] = (f16)(y * siluf_(g));
    }
}

// ---------------------------------------------------------------------------
// L9: out = y @ W_out (256 blocks)
// ---------------------------------------------------------------------------
__global__ __launch_bounds__(256) void k_gemm2(Args a)
{
    __shared__ __align__(16) f16 As[64 * 64];
    __shared__ __align__(16) f16 Bs[128 * 64];
    gemm_tile<64, 128, INTER, float>(a.yh, a.W_out_t, a.out, HID,
                                     (int)blockIdx.x & 7, (int)blockIdx.x >> 3,
                                     threadIdx.x, As, Bs);
}

// ---------------------------------------------------------------------------
extern "C" void kernel_launch(void* const* d_in, const int* in_sizes, int n_in,
                              void* d_out, int out_size, void* d_ws, size_t ws_size,
                              hipStream_t stream)
{
    float* ws = (float*)d_ws;
    Args a;
    a.x      = (const float*)d_in[0];
    a.W_in   = (const float*)d_in[1];
    a.conv_w = (const float*)d_in[2];
    a.conv_b = (const float*)d_in[3];
    a.W_x    = (const float*)d_in[4];
    a.W_dt   = (const float*)d_in[5];
    a.b_dt   = (const float*)d_in[6];
    a.A_log  = (const float*)d_in[7];
    a.Dv     = (const float*)d_in[8];
    a.W_out  = (const float*)d_in[9];
    a.out    = (float*)d_out;

    a.projh  = (f16*)ws;
    a.hh     = (f16*)(ws + 4194304);
    a.dtbh   = (f16*)(ws + 6291456);
    a.yh     = (f16*)(ws + 8388608);
    a.xh     = (f16*)(ws + 10485760);
    a.W_in_t = (f16*)(ws + 11534336);
    a.W_out_t= (f16*)(ws + 13631488);
    a.WxT    = (f16*)(ws + 14680064);
    a.tsh    = (f16*)(ws + 14778368);
    a.WdtT   = (f16*)(ws + 14843904);
    a.ssm_p  = ws + 14909440;
    a.parts  = (f16*)(ws + 15106048);
    a.Sbuf   = ws + 16678912;
    a.Pbuf   = ws + 18776064;
    a.Cin    = ws + 20873216;

    k_prep_a<<<6144, 256, 0, stream>>>(a);   // x cvt + W_in^T
    k_gemm1r<<<2880, 256, 0, stream>>>(a);   // proj GEMM + rider transposes
    k_hwxc  <<<256,  256, 0, stream>>>(a);   // fused conv+silu + hwx MFMA
    k_reduce<<<96,   256, 0, stream>>>(a);
    k_dt    <<<256,  256, 0, stream>>>(a);
    k_pass1 <<<512,  256, 0, stream>>>(a);
    k_pass2 <<<128,  256, 0, stream>>>(a);
    k_pass3 <<<512,  256, 0, stream>>>(a);
    k_gemm2 <<<256,  256, 0, stream>>>(a);
}

// Round 13
// 180.395 us; speedup vs baseline: 5.8917x; 1.0590x over previous
//
#include <hip/hip_runtime.h>
#include <math.h>

#define SEQ   2048
#define HID   1024
#define INTER 2048
#define DST   16
#define DTR   64
#define NP    96   // DTR + 2*DST
#define NC    64   // scan chunks
#define LCH   32   // steps per chunk (NC*LCH == SEQ)
#define KS    16   // split-K factor for h @ W_x

typedef _Float16 f16;
typedef _Float16 f16x8 __attribute__((ext_vector_type(8)));
typedef _Float16 f16x4v __attribute__((ext_vector_type(4)));
typedef _Float16 f16x2 __attribute__((ext_vector_type(2)));
typedef float f32x4 __attribute__((ext_vector_type(4)));

__device__ __forceinline__ float sigmoidf_(float x) { return 1.0f / (1.0f + expf(-x)); }
__device__ __forceinline__ float siluf_(float x)    { return x * sigmoidf_(x); }
__device__ __forceinline__ float softplusf_(float x){ return (x > 20.0f) ? x : log1pf(expf(x)); }

struct Args {
    const float* x; const float* W_in; const float* W_out; const float* W_x; const float* W_dt;
    const float* conv_w; const float* conv_b; const float* b_dt; const float* A_log; const float* Dv;
    float* out;
    f16* xh; f16* W_in_t; f16* W_out_t; f16* WxT; f16* WdtT;
    f16* projh; f16* hh; f16* dtbh; f16* yh; f16* tsh; f16* parts;
    float* ssm_p; f16x2* SPbuf; f16* Cin;
};

// ---------------------------------------------------------------------------
// 32x32 tile transpose f32 -> f16^T through LDS scratch t[32][33]
// ---------------------------------------------------------------------------
__device__ __forceinline__ void tile_transpose(const float* __restrict__ W,
                                               f16* __restrict__ Wt,
                                               int K, int N, int bx, int by,
                                               int tid, float* t)
{
    const int n0 = bx * 32, k0 = by * 32;
    const int j = tid & 31, i0 = tid >> 5;   // i0: 0..7
#pragma unroll
    for (int r = 0; r < 4; ++r)
        t[(i0 + r * 8) * 33 + j] = W[(size_t)(k0 + i0 + r * 8) * N + n0 + j];
    __syncthreads();
#pragma unroll
    for (int r = 0; r < 4; ++r)
        Wt[(size_t)(n0 + i0 + r * 8) * K + k0 + j] = (f16)t[j * 33 + i0 + r * 8];
}

// ---------------------------------------------------------------------------
// m97-structure MFMA f16 GEMM tile: C[M,N] OutT = Ah[M,KTOT] @ Bt[N,KTOT]^T
// ---------------------------------------------------------------------------
template<int BM, int BN, int KTOT, typename OutT>
__device__ __forceinline__ void gemm_tile(const f16* __restrict__ Ah,
                                          const f16* __restrict__ Bt,
                                          OutT* __restrict__ C, int N,
                                          int bx, int by, int tid,
                                          f16* As, f16* Bs)
{
    constexpr int BK = 64;
    const int wid = tid >> 6, lane = tid & 63;
    const int wr = wid >> 1, wc = wid & 1;
    const int m0 = by * BM, n0 = bx * BN;
    const int l15 = lane & 15, lhi = lane >> 4;
    constexpr int MR = BM / 32;
    constexpr int NR = BN / 32;

    f32x4 acc[MR][NR] = {};

    for (int k0 = 0; k0 < KTOT; k0 += BK) {
        constexpr int CA = BM * BK * 2 / 1024;
#pragma unroll
        for (int c0 = 0; c0 < CA; c0 += 4) {
            int c = c0 + wid;
            int e = c * 64 + lane;
            int row = e >> 3, seg = e & 7;
            __builtin_amdgcn_global_load_lds(
                (const __attribute__((address_space(1))) unsigned int*)
                    (Ah + (size_t)(m0 + row) * KTOT + k0 + seg * 8),
                (__attribute__((address_space(3))) unsigned int*)(As + c * 512),
                16, 0, 0);
        }
        constexpr int CB = BN * BK * 2 / 1024;
#pragma unroll
        for (int c0 = 0; c0 < CB; c0 += 4) {
            int c = c0 + wid;
            int e = c * 64 + lane;
            int row = e >> 3, seg = e & 7;
            __builtin_amdgcn_global_load_lds(
                (const __attribute__((address_space(1))) unsigned int*)
                    (Bt + (size_t)(n0 + row) * KTOT + k0 + seg * 8),
                (__attribute__((address_space(3))) unsigned int*)(Bs + c * 512),
                16, 0, 0);
        }
        __syncthreads();

#pragma unroll
        for (int kk = 0; kk < BK; kk += 32) {
            f16x8 af[MR], bf[NR];
#pragma unroll
            for (int i = 0; i < MR; ++i)
                af[i] = *(const f16x8*)&As[(wr * (BM / 2) + i * 16 + l15) * BK + kk + lhi * 8];
#pragma unroll
            for (int n = 0; n < NR; ++n)
                bf[n] = *(const f16x8*)&Bs[(wc * (BN / 2) + n * 16 + l15) * BK + kk + lhi * 8];
#pragma unroll
            for (int i = 0; i < MR; ++i)
#pragma unroll
                for (int n = 0; n < NR; ++n)
                    acc[i][n] = __builtin_amdgcn_mfma_f32_16x16x32_f16(af[i], bf[n], acc[i][n], 0, 0, 0);
        }
        __syncthreads();
    }

    // C/D map: col = lane&15, row = (lane>>4)*4 + reg
#pragma unroll
    for (int i = 0; i < MR; ++i)
#pragma unroll
        for (int n = 0; n < NR; ++n)
#pragma unroll
            for (int r = 0; r < 4; ++r)
                C[(size_t)(m0 + wr * (BM / 2) + i * 16 + lhi * 4 + r) * N
                  + n0 + wc * (BN / 2) + n * 16 + l15] = (OutT)acc[i][n][r];
}

// ---------------------------------------------------------------------------
// L1: x->f16 + all 4 weight transposes (8512 blocks)
// ---------------------------------------------------------------------------
__global__ __launch_bounds__(256) void k_prep(Args a)
{
    __shared__ float t[32 * 33];
    const int v = blockIdx.x, tid = threadIdx.x;
    if (v < 2048) {
        int i = (v * 256 + tid) * 4;
        float4 w = *(const float4*)&a.x[i];
        f16x4v o;
        o.x = (f16)w.x; o.y = (f16)w.y; o.z = (f16)w.z; o.w = (f16)w.w;
        *(f16x4v*)&a.xh[i] = o;
    } else if (v < 6144) {
        int q = v - 2048;                       // W_in: K=1024, N=4096
        tile_transpose(a.W_in, a.W_in_t, HID, 4096, q & 127, q >> 7, tid, t);
    } else if (v < 8192) {
        int q = v - 6144;                       // W_out: K=2048, N=1024
        tile_transpose(a.W_out, a.W_out_t, INTER, HID, q & 31, q >> 5, tid, t);
    } else if (v < 8384) {
        int q = v - 8192;                       // W_x: K=2048, N=96
        tile_transpose(a.W_x, a.WxT, INTER, NP, q % 3, q / 3, tid, t);
    } else {
        int q = v - 8384;                       // W_dt: K=64, N=2048
        tile_transpose(a.W_dt, a.WdtT, DTR, INTER, q & 63, q >> 6, tid, t);
    }
}

// ---------------------------------------------------------------------------
// L2: proj = x @ W_in (512 blocks)
// ---------------------------------------------------------------------------
__global__ __launch_bounds__(256) void k_gemm1(Args a)
{
    __shared__ __align__(16) f16 As[128 * 64];
    __shared__ __align__(16) f16 Bs[128 * 64];
    gemm_tile<128, 128, HID, f16>(a.xh, a.W_in_t, a.projh, 4096,
                                  (int)blockIdx.x % 32, (int)blockIdx.x / 32,
                                  threadIdx.x, As, Bs);
}

// ---------------------------------------------------------------------------
// L3: fused conv+silu into hwx A-staging; writes hh as byproduct. (256 blocks)
// ---------------------------------------------------------------------------
__global__ __launch_bounds__(256) void k_hwxc(Args a)
{
    constexpr int BM = 128, BN = 96, BK = 64;
    __shared__ __align__(16) f16 As[BM * BK];
    __shared__ __align__(16) f16 Bs[BN * BK];

    const int v = blockIdx.x;
    const int bxm = v & 15, ks = v >> 4;
    const int tid = threadIdx.x;
    const int wid = tid >> 6, lane = tid & 63;
    const int wr = wid >> 1, wc = wid & 1;
    const int m0 = bxm * BM;
    const int l15 = lane & 15, lhi = lane >> 4;

    f32x4 acc[4][3] = {};

    for (int k0 = ks * 128; k0 < ks * 128 + 128; k0 += BK) {
#pragma unroll
        for (int c0 = 0; c0 < 12; c0 += 4) {
            int c = c0 + wid;
            int e = c * 64 + lane;
            int row = e >> 3, seg = e & 7;
            __builtin_amdgcn_global_load_lds(
                (const __attribute__((address_space(1))) unsigned int*)
                    (a.WxT + (size_t)row * INTER + k0 + seg * 8),
                (__attribute__((address_space(3))) unsigned int*)(Bs + c * 512),
                16, 0, 0);
        }
        // A staging: conv+silu in registers -> LDS + hh byproduct
#pragma unroll
        for (int i = 0; i < 4; ++i) {
            int u = tid + i * 256;
            int row = u >> 3, seg = u & 7;
            int s = m0 + row;
            int c8 = k0 + seg * 8;
            float av[8];
#pragma unroll
            for (int j = 0; j < 8; ++j) av[j] = a.conv_b[c8 + j];
#pragma unroll
            for (int k = 0; k < 4; ++k) {
                int sp = s + k - 3;
                if (sp >= 0) {
                    f16x8 p = *(const f16x8*)&a.projh[(size_t)sp * 4096 + c8];
#pragma unroll
                    for (int j = 0; j < 8; ++j)
                        av[j] = fmaf((float)p[j], a.conv_w[k * INTER + c8 + j], av[j]);
                }
            }
            f16x8 o;
#pragma unroll
            for (int j = 0; j < 8; ++j) o[j] = (f16)siluf_(av[j]);
            *(f16x8*)&As[row * 64 + seg * 8] = o;
            *(f16x8*)&a.hh[(size_t)s * INTER + c8] = o;
        }
        __syncthreads();

#pragma unroll
        for (int kk = 0; kk < BK; kk += 32) {
            f16x8 af[4], bf[3];
#pragma unroll
            for (int i = 0; i < 4; ++i)
                af[i] = *(const f16x8*)&As[(wr * 64 + i * 16 + l15) * BK + kk + lhi * 8];
#pragma unroll
            for (int n = 0; n < 3; ++n)
                bf[n] = *(const f16x8*)&Bs[(wc * 48 + n * 16 + l15) * BK + kk + lhi * 8];
#pragma unroll
            for (int i = 0; i < 4; ++i)
#pragma unroll
                for (int n = 0; n < 3; ++n)
                    acc[i][n] = __builtin_amdgcn_mfma_f32_16x16x32_f16(af[i], bf[n], acc[i][n], 0, 0, 0);
        }
        __syncthreads();
    }

    f16* P = a.parts + (size_t)ks * (SEQ * NP);
#pragma unroll
    for (int i = 0; i < 4; ++i)
#pragma unroll
        for (int n = 0; n < 3; ++n)
#pragma unroll
            for (int r = 0; r < 4; ++r)
                P[(size_t)(m0 + wr * 64 + i * 16 + lhi * 4 + r) * NP
                  + wc * 48 + n * 16 + l15] = (f16)acc[i][n][r];
}

// ---------------------------------------------------------------------------
// L4: reduce 16 f16 planes -> ssm_p (B,C f32) + tsh (ts f16) (96 blocks)
// ---------------------------------------------------------------------------
__global__ __launch_bounds__(256) void k_reduce(Args a)
{
    int i8 = (blockIdx.x * 256 + threadIdx.x) * 8;
    int s = i8 / NP, j0 = i8 % NP;
    float acc[8] = {};
#pragma unroll
    for (int c = 0; c < KS; ++c) {
        f16x8 w = *(const f16x8*)&a.parts[(size_t)c * (SEQ * NP) + i8];
#pragma unroll
        for (int j = 0; j < 8; ++j) acc[j] += (float)w[j];
    }
    if (j0 < DTR) {
        f16x8 o;
#pragma unroll
        for (int j = 0; j < 8; ++j) o[j] = (f16)acc[j];
        *(f16x8*)&a.tsh[(size_t)s * DTR + j0] = o;
    } else {
        *(float4*)&a.ssm_p[(size_t)s * NP + j0]     = make_float4(acc[0], acc[1], acc[2], acc[3]);
        *(float4*)&a.ssm_p[(size_t)s * NP + j0 + 4] = make_float4(acc[4], acc[5], acc[6], acc[7]);
    }
}

// ---------------------------------------------------------------------------
// L5: dt = softplus(ts @ W_dt + b_dt) -> f16 (256 blocks)
// ---------------------------------------------------------------------------
__global__ __launch_bounds__(256) void k_dt(Args a)
{
    constexpr int BK = 64;
    __shared__ __align__(16) f16 As[128 * 64];
    __shared__ __align__(16) f16 Bs[128 * 64];
    const int v = blockIdx.x, tid = threadIdx.x;
    const int bx = v & 15, by = v >> 4;
    const int wid = tid >> 6, lane = tid & 63;
    const int wr = wid >> 1, wc = wid & 1;
    const int m0 = by * 128, n0 = bx * 128;
    const int l15 = lane & 15, lhi = lane >> 4;
    f32x4 acc[4][4] = {};

#pragma unroll
    for (int c0 = 0; c0 < 16; c0 += 4) {
        int c = c0 + wid;
        int e = c * 64 + lane;
        int row = e >> 3, seg = e & 7;
        __builtin_amdgcn_global_load_lds(
            (const __attribute__((address_space(1))) unsigned int*)
                (a.tsh + (size_t)(m0 + row) * DTR + seg * 8),
            (__attribute__((address_space(3))) unsigned int*)(As + c * 512),
            16, 0, 0);
        __builtin_amdgcn_global_load_lds(
            (const __attribute__((address_space(1))) unsigned int*)
                (a.WdtT + (size_t)(n0 + row) * DTR + seg * 8),
            (__attribute__((address_space(3))) unsigned int*)(Bs + c * 512),
            16, 0, 0);
    }
    __syncthreads();

#pragma unroll
    for (int kk = 0; kk < 64; kk += 32) {
        f16x8 af[4], bf[4];
#pragma unroll
        for (int i = 0; i < 4; ++i)
            af[i] = *(const f16x8*)&As[(wr * 64 + i * 16 + l15) * BK + kk + lhi * 8];
#pragma unroll
        for (int n = 0; n < 4; ++n)
            bf[n] = *(const f16x8*)&Bs[(wc * 64 + n * 16 + l15) * BK + kk + lhi * 8];
#pragma unroll
        for (int i = 0; i < 4; ++i)
#pragma unroll
            for (int n = 0; n < 4; ++n)
                acc[i][n] = __builtin_amdgcn_mfma_f32_16x16x32_f16(af[i], bf[n], acc[i][n], 0, 0, 0);
    }

#pragma unroll
    for (int i = 0; i < 4; ++i)
#pragma unroll
        for (int n = 0; n < 4; ++n) {
            int col = n0 + wc * 64 + n * 16 + l15;
            float bv = a.b_dt[col];
#pragma unroll
            for (int r = 0; r < 4; ++r)
                a.dtbh[(size_t)(m0 + wr * 64 + i * 16 + lhi * 4 + r) * INTER + col] =
                    (f16)softplusf_(acc[i][n][r] + bv);
        }
}

// ---------------------------------------------------------------------------
// L6: scan pass1 -> interleaved {S,P} f16x2 (512 blocks)
// ---------------------------------------------------------------------------
__global__ __launch_bounds__(256) void k_pass1(Args a)
{
    __shared__ float Bsc[LCH * DST];
    const int v = blockIdx.x, tid = threadIdx.x;
    const int hblk = v >> 6, c = v & 63;
    const int h = hblk * 256 + tid;
    const int s0 = c * LCH;
    for (int j = tid; j < LCH * DST; j += 256) {
        int r = j >> 4, dd = j & 15;
        Bsc[r * DST + dd] = a.ssm_p[(size_t)(s0 + r) * NP + DTR + dd];
    }
    __syncthreads();

    float A[DST], st[DST];
#pragma unroll
    for (int d = 0; d < DST; ++d) {
        A[d] = -__expf(a.A_log[(size_t)h * DST + d]);
        st[d] = 0.0f;
    }
    float dtsum = 0.0f;
#pragma unroll 2
    for (int r = 0; r < LCH; ++r) {
        float dtv = (float)a.dtbh[(size_t)(s0 + r) * INTER + h];
        float hv  = (float)a.hh[(size_t)(s0 + r) * INTER + h];
        float dh = dtv * hv;
        dtsum += dtv;
#pragma unroll
        for (int d = 0; d < DST; ++d) {
            float da = __expf(dtv * A[d]);
            st[d] = fmaf(da, st[d], dh * Bsc[r * DST + d]);
        }
    }
    size_t base = ((size_t)c * INTER + h) * DST;
#pragma unroll
    for (int d = 0; d < DST; ++d) {
        f16x2 sp;
        sp.x = (f16)st[d];
        sp.y = (f16)__expf(A[d] * dtsum);
        a.SPbuf[base + d] = sp;
    }
}

// ---------------------------------------------------------------------------
// L7: scan pass2 over chunk aggregates (128 blocks)
// ---------------------------------------------------------------------------
__global__ __launch_bounds__(256) void k_pass2(Args a)
{
    int i = blockIdx.x * 256 + threadIdx.x;   // over INTER*DST = 32768
    float carry = 0.0f;
#pragma unroll 8
    for (int c = 0; c < NC; ++c) {
        size_t idx = (size_t)c * (INTER * DST) + i;
        f16x2 sp = a.SPbuf[idx];
        a.Cin[idx] = (f16)carry;
        carry = fmaf((float)sp.y, carry, (float)sp.x);
    }
}

// ---------------------------------------------------------------------------
// L8: scan pass3 + fused epilogue -> yh (512 blocks)
// ---------------------------------------------------------------------------
__global__ __launch_bounds__(256) void k_pass3(Args a)
{
    __shared__ float Bsc[LCH * DST];
    __shared__ float Csc[LCH * DST];
    const int v = blockIdx.x, tid = threadIdx.x;
    const int hblk = v >> 6, c = v & 63;
    const int h = hblk * 256 + tid;
    const int s0 = c * LCH;
    for (int j = tid; j < LCH * DST; j += 256) {
        int r = j >> 4, dd = j & 15;
        Bsc[r * DST + dd] = a.ssm_p[(size_t)(s0 + r) * NP + DTR + dd];
        Csc[r * DST + dd] = a.ssm_p[(size_t)(s0 + r) * NP + DTR + DST + dd];
    }
    __syncthreads();

    float A[DST], st[DST];
    size_t base = ((size_t)c * INTER + h) * DST;
#pragma unroll
    for (int d = 0; d < DST; ++d) {
        A[d] = -__expf(a.A_log[(size_t)h * DST + d]);
        st[d] = (float)a.Cin[base + d];
    }
    const float Dvv = a.Dv[h];

#pragma unroll 2
    for (int r = 0; r < LCH; ++r) {
        float dtv = (float)a.dtbh[(size_t)(s0 + r) * INTER + h];
        float hv  = (float)a.hh[(size_t)(s0 + r) * INTER + h];
        float g   = (float)a.projh[(size_t)(s0 + r) * 4096 + INTER + h];
        float dh = dtv * hv;
        float y = 0.0f;
#pragma unroll
        for (int d = 0; d < DST; ++d) {
            float da = __expf(dtv * A[d]);
            st[d] = fmaf(da, st[d], dh * Bsc[r * DST + d]);
            y = fmaf(st[d], Csc[r * DST + d], y);
        }
        y = fmaf(hv, Dvv, y);
        a.yh[(size_t)(s0 + r) * INTER + h] = (f16)(y * siluf_(g));
    }
}

// ---------------------------------------------------------------------------
// L9: out = y @ W_out (256 blocks)
// ---------------------------------------------------------------------------
__global__ __launch_bounds__(256) void k_gemm2(Args a)
{
    __shared__ __align__(16) f16 As[64 * 64];
    __shared__ __align__(16) f16 Bs[128 * 64];
    gemm_tile<64, 128, INTER, float>(a.yh, a.W_out_t, a.out, HID,
                                     (int)blockIdx.x & 7, (int)blockIdx.x >> 3,
                                     threadIdx.x, As, Bs);
}

// ---------------------------------------------------------------------------
extern "C" void kernel_launch(void* const* d_in, const int* in_sizes, int n_in,
                              void* d_out, int out_size, void* d_ws, size_t ws_size,
                              hipStream_t stream)
{
    float* ws = (float*)d_ws;
    Args a;
    a.x      = (const float*)d_in[0];
    a.W_in   = (const float*)d_in[1];
    a.conv_w = (const float*)d_in[2];
    a.conv_b = (const float*)d_in[3];
    a.W_x    = (const float*)d_in[4];
    a.W_dt   = (const float*)d_in[5];
    a.b_dt   = (const float*)d_in[6];
    a.A_log  = (const float*)d_in[7];
    a.Dv     = (const float*)d_in[8];
    a.W_out  = (const float*)d_in[9];
    a.out    = (float*)d_out;

    a.projh  = (f16*)ws;                     // SEQ x 4096 halves
    a.hh     = (f16*)(ws + 4194304);         // SEQ x INTER
    a.dtbh   = (f16*)(ws + 6291456);         // SEQ x INTER
    a.yh     = (f16*)(ws + 8388608);         // SEQ x INTER
    a.xh     = (f16*)(ws + 10485760);        // SEQ x HID
    a.W_in_t = (f16*)(ws + 11534336);        // 4096 x HID
    a.W_out_t= (f16*)(ws + 13631488);        // HID x INTER
    a.WxT    = (f16*)(ws + 14680064);        // 96 x INTER
    a.tsh    = (f16*)(ws + 14778368);        // SEQ x DTR
    a.WdtT   = (f16*)(ws + 14843904);        // INTER x DTR
    a.ssm_p  = ws + 14909440;                // SEQ x NP f32
    a.parts  = (f16*)(ws + 15106048);        // KS x SEQ x NP halves
    a.SPbuf  = (f16x2*)(ws + 16678912);      // NC x INTER x DST f16x2
    a.Cin    = (f16*)(ws + 18776064);        // NC x INTER x DST f16

    k_prep  <<<8512, 256, 0, stream>>>(a);
    k_gemm1 <<<512,  256, 0, stream>>>(a);
    k_hwxc  <<<256,  256, 0, stream>>>(a);
    k_reduce<<<96,   256, 0, stream>>>(a);
    k_dt    <<<256,  256, 0, stream>>>(a);
    k_pass1 <<<512,  256, 0, stream>>>(a);
    k_pass2 <<<128,  256, 0, stream>>>(a);
    k_pass3 <<<512,  256, 0, stream>>>(a);
    k_gemm2 <<<256,  256, 0, stream>>>(a);
}